// Round 13
// baseline (141.041 us; speedup 1.0000x reference)
//
#include <hip/hip_runtime.h>
#include <math.h>

// AtomQueryFieldNet: NQ=4096, NA=512, pair MLP 18->64->64->32->1, cutoff mask,
// per-query 3-vector reduction, 3->64->3 head.
//
// R13: 8-wave blocks (512 thr), 2 queries/block, shared chunk pool.
//  - Residency data R8-R12: waves/CU grows with block size (1-wave blocks ->
//    ~5 waves/CU; 4-wave -> ~7.3). 8-wave blocks target ~16 waves/CU.
//  - Waves 0-3 compact q0 (128-atom segments), 4-7 compact q1 (two-pass
//    deterministic prefix, 2 barriers). Then ALL 8 waves pull 32-pair chunks
//    round-robin from the COMBINED pool (smooths 35..270 count imbalance).
//    Chunk->query is wave-uniform; two accumulator triples per wave.
//  - Hot loop byte-identical to R12 (transposed MFMA h^T=W^T X^T, NT=2,
//    per-wave exchange, fused L4+accumulation).
//  - LDS ~32.7KB -> 4 blocks/CU ceiling. repack pre-kernel unchanged.
//  - fp16 in / fp32 accum; absmax ~0.0156.

typedef _Float16 f16x8 __attribute__((ext_vector_type(8)));
typedef _Float16 f16x4 __attribute__((ext_vector_type(4)));
typedef _Float16 f16x2 __attribute__((ext_vector_type(2)));
typedef float    f32x4 __attribute__((ext_vector_type(4)));

#define CAP 352   // max in-range atoms/query (geometric max ~270)
#define XP2 72    // exchange row pitch in f16 (144B rows; b64/b128 aligned)
#define NT  2     // tiles (16 pairs) interleaved per chunk

// ---- repack: weights -> MFMA fragment order in d_ws (see R9) ----
__global__ __launch_bounds__(64) void repack_kernel(
    const float* __restrict__ W1, const float* __restrict__ b1,
    const float* __restrict__ W2, const float* __restrict__ b2,
    const float* __restrict__ W3, const float* __restrict__ b3,
    const float* __restrict__ W4, char* __restrict__ ws)
{
    const int b = blockIdx.x, l = threadIdx.x;
    const int col = l & 15, quad = l >> 4;
    if (b < 16) {
        f16x8 v;
        #pragma unroll
        for (int j = 0; j < 8; ++j) {
            const int k = quad*8 + j;
            float x;
            if (b < 4) {
                const int mt = b;
                x = (k < 18) ? W1[k*64 + mt*16 + col]
                             : (k == 18 ? b1[mt*16 + col] : 0.0f);
            } else if (b < 12) {
                const int kc = (b-4) >> 2, mt = (b-4) & 3;
                x = W2[(kc*32 + k)*64 + mt*16 + col];
            } else {
                const int kc = (b-12) >> 1, mt = (b-12) & 1;
                x = W3[(kc*32 + k)*32 + mt*16 + col];
            }
            v[j] = (_Float16)x;
        }
        *(f16x8*)(ws + (b*64 + l)*16) = v;
    } else {
        const int d = b - 16;
        float o[4];
        #pragma unroll
        for (int rr = 0; rr < 4; ++rr) {
            const int idx = quad*4 + rr;
            if (d < 4)      o[rr] = b2[d*16 + idx];
            else if (d < 6) o[rr] = b3[(d-4)*16 + idx];
            else            o[rr] = W4[(d-6)*16 + idx];
        }
        *(float4*)(ws + 16384 + (d*64 + l)*16) = make_float4(o[0],o[1],o[2],o[3]);
    }
}

__global__ __launch_bounds__(512, 1) void aqfn_kernel(
    const float* __restrict__ atom_pos,   // (512,3)
    const float* __restrict__ atom_feat,  // (512,2)
    const float* __restrict__ query_pos,  // (4096,3)
    const float* __restrict__ b4,         // (1)
    const float* __restrict__ W5, const float* __restrict__ b5,  // (3,64),(64)
    const float* __restrict__ W6, const float* __restrict__ b6,  // (64,3),(3)
    const char*  __restrict__ ws,         // repacked weights
    float* __restrict__ out)              // (4096,3)
{
    __shared__ __align__(16) float4   rbuf[2][CAP];         // per-query lists
    __shared__ __align__(16) f16x2    fbuf[2][CAP];
    __shared__ __align__(16) _Float16 exch[8][NT][16*XP2];  // per-wave exchange
    __shared__ float wred[8][2][3];
    __shared__ int   wcnt[8];

    const int tid  = threadIdx.x;
    const int wave = __builtin_amdgcn_readfirstlane(tid >> 6);   // 0..7
    const int lane = tid & 63;
    const int col  = lane & 15;
    const int quad = lane >> 4;
    const int qsel = wave >> 2;          // which query this wave compacts
    const int seg  = wave & 3;           // 128-atom segment within that query

    // ---- fragment preload: 24 coalesced dwordx4 loads (per wave) ----
    const f16x8*  wsf = (const f16x8*)ws;
    const float4* wsb = (const float4*)(ws + 16384);
    f16x8 w1f[4], w2f[2][4], w3f[2][2];
    #pragma unroll
    for (int mt = 0; mt < 4; ++mt) w1f[mt] = wsf[mt*64 + lane];
    #pragma unroll
    for (int kc = 0; kc < 2; ++kc)
        #pragma unroll
        for (int mt = 0; mt < 4; ++mt) w2f[kc][mt] = wsf[(4 + kc*4 + mt)*64 + lane];
    #pragma unroll
    for (int kc = 0; kc < 2; ++kc)
        #pragma unroll
        for (int mt = 0; mt < 2; ++mt) w3f[kc][mt] = wsf[(12 + kc*2 + mt)*64 + lane];
    float4 b2v[4], b3v[2], w4v[2];
    #pragma unroll
    for (int mt = 0; mt < 4; ++mt) b2v[mt] = wsb[mt*64 + lane];
    #pragma unroll
    for (int mt = 0; mt < 2; ++mt) { b3v[mt] = wsb[(4+mt)*64 + lane];
                                     w4v[mt] = wsb[(6+mt)*64 + lane]; }
    const float b4v = b4[0];

    const int qg = blockIdx.x*2 + qsel;       // query this wave compacts
    const float qx = query_pos[qg*3+0];
    const float qy = query_pos[qg*3+1];
    const float qz = query_pos[qg*3+2];

    // ---- pass 1: ballots over segment [seg*128, +128) of query qsel ----
    float rxv[2], ryv[2], rzv[2], dv[2], f0v[2], f1v[2];
    unsigned long long msk[2];
    int mycnt = 0;
    #pragma unroll
    for (int it = 0; it < 2; ++it) {
        const int a = seg*128 + it*64 + lane;
        const float rx = qx - atom_pos[a*3+0];
        const float ry = qy - atom_pos[a*3+1];
        const float rz = qz - atom_pos[a*3+2];
        const float ex = __fadd_rn(rx, 1e-12f);
        const float ey = __fadd_rn(ry, 1e-12f);
        const float ez = __fadd_rn(rz, 1e-12f);
        const float dd = __fadd_rn(__fadd_rn(__fmul_rn(ex,ex), __fmul_rn(ey,ey)),
                                   __fmul_rn(ez,ez));
        const float dist = sqrtf(dd);
        rxv[it] = rx; ryv[it] = ry; rzv[it] = rz; dv[it] = dist;
        f0v[it] = atom_feat[a*2+0]; f1v[it] = atom_feat[a*2+1];
        msk[it] = __ballot(dist <= 6.0f);
        mycnt  += (int)__popcll(msk[it]);
    }
    if (lane == 0) wcnt[wave] = mycnt;
    __syncthreads();

    // per-query exclusive prefix + both counts
    int base = 0, cnt0 = 0, cnt1 = 0;
    #pragma unroll
    for (int w = 0; w < 4; ++w) {
        cnt0 += wcnt[w];
        cnt1 += wcnt[4+w];
        if ((qsel*4 + w) < wave) base += wcnt[qsel*4 + w];
    }
    if (cnt0 > CAP) cnt0 = CAP;
    if (cnt1 > CAP) cnt1 = CAP;

    // ---- pass 2: prefix-offset writes into this query's shared list ----
    {
        int off0 = base;
        #pragma unroll
        for (int it = 0; it < 2; ++it) {
            const bool in = (msk[it] >> lane) & 1ull;
            const int  p  = off0 + (int)__popcll(msk[it] & ((1ull << lane) - 1ull));
            if (in && p < CAP) {
                rbuf[qsel][p] = make_float4(rxv[it], ryv[it], rzv[it], dv[it]);
                fbuf[qsel][p] = f16x2{(_Float16)f0v[it], (_Float16)f1v[it]};
            }
            off0 += (int)__popcll(msk[it]);
        }
    }
    __syncthreads();

    // ---- MLP over combined chunk pool: round-robin across 8 waves ----
    float acc[2][3] = {{0.f,0.f,0.f},{0.f,0.f,0.f}};
    const int nch0 = (cnt0 + (NT*16 - 1)) / (NT*16);
    const int nch1 = (cnt1 + (NT*16 - 1)) / (NT*16);
    const int ntot = nch0 + nch1;

    #pragma unroll 1
    for (int g = wave; g < ntot; g += 8) {
        const int cq    = (g < nch0) ? 0 : 1;            // wave-uniform
        const int lc    = (g < nch0) ? g : (g - nch0);
        const int count = (cq == 0) ? cnt0 : cnt1;
        const float4* __restrict__ rb = &rbuf[cq][0];
        const f16x2*  __restrict__ fb = &fbuf[cq][0];
        const int row0 = lc * (NT*16);

        float4 rv[NT]; f16x2 ffv[NT];
        #pragma unroll
        for (int u = 0; u < NT; ++u) {
            int pr = row0 + u*16 + col;
            if (pr >= count) pr = count - 1;
            rv[u]  = rb[pr];
            ffv[u] = fb[pr];
        }

        // X B-frags: B[k=quad*8+j][n=col]; x = [f0,f1,rbf(16),1(bias),0...]
        f16x8 xa[NT];
        #pragma unroll
        for (int u = 0; u < NT; ++u) {
            const float dist = rv[u].w;
            #pragma unroll
            for (int j = 0; j < 8; ++j) {
                const int k = quad*8 + j;
                const float tt = dist - 0.4f * (float)(k - 2);  // centers linspace(0,6,16)
                float v = __expf(-10.0f * tt * tt);
                v = (k < 18) ? v : 0.0f;
                _Float16 xv = (_Float16)v;
                if (k == 18) xv = (_Float16)1.0f;      // bias slot (b1 in W1)
                if (j == 0) xv = (quad == 0) ? ffv[u][0] : xv;
                if (j == 1) xv = (quad == 0) ? ffv[u][1] : xv;
                xa[u][j] = xv;
            }
        }

        // ---- L1 transposed: h1^T[mt*16+quad*4+rr][pair=col] ----
        #pragma unroll
        for (int u = 0; u < NT; ++u)
            #pragma unroll
            for (int mt = 0; mt < 4; ++mt) {
                f32x4 c = {0.f, 0.f, 0.f, 0.f};
                c = __builtin_amdgcn_mfma_f32_16x16x32_f16(w1f[mt], xa[u], c, 0, 0, 0);
                f16x4 pk = {(_Float16)fmaxf(c[0],0.f), (_Float16)fmaxf(c[1],0.f),
                            (_Float16)fmaxf(c[2],0.f), (_Float16)fmaxf(c[3],0.f)};
                *(f16x4*)&exch[wave][u][col*XP2 + mt*16 + quad*4] = pk;
            }
        f16x8 a2[NT][2];
        #pragma unroll
        for (int u = 0; u < NT; ++u)
            #pragma unroll
            for (int kc = 0; kc < 2; ++kc)
                a2[u][kc] = *(const f16x8*)&exch[wave][u][col*XP2 + kc*32 + quad*8];

        // ---- L2 transposed ----
        #pragma unroll
        for (int u = 0; u < NT; ++u)
            #pragma unroll
            for (int mt = 0; mt < 4; ++mt) {
                f32x4 c = {b2v[mt].x, b2v[mt].y, b2v[mt].z, b2v[mt].w};
                c = __builtin_amdgcn_mfma_f32_16x16x32_f16(w2f[0][mt], a2[u][0], c, 0, 0, 0);
                c = __builtin_amdgcn_mfma_f32_16x16x32_f16(w2f[1][mt], a2[u][1], c, 0, 0, 0);
                f16x4 pk = {(_Float16)fmaxf(c[0],0.f), (_Float16)fmaxf(c[1],0.f),
                            (_Float16)fmaxf(c[2],0.f), (_Float16)fmaxf(c[3],0.f)};
                *(f16x4*)&exch[wave][u][col*XP2 + mt*16 + quad*4] = pk;
            }
        f16x8 a3[NT][2];
        #pragma unroll
        for (int u = 0; u < NT; ++u)
            #pragma unroll
            for (int kc = 0; kc < 2; ++kc)
                a3[u][kc] = *(const f16x8*)&exch[wave][u][col*XP2 + kc*32 + quad*8];

        // ---- L3 transposed + L4 partial + quad-reduce + fused accumulation ----
        #pragma unroll
        for (int u = 0; u < NT; ++u) {
            float s = 0.f;
            #pragma unroll
            for (int mt = 0; mt < 2; ++mt) {
                f32x4 c = {b3v[mt].x, b3v[mt].y, b3v[mt].z, b3v[mt].w};
                c = __builtin_amdgcn_mfma_f32_16x16x32_f16(w3f[0][mt], a3[u][0], c, 0, 0, 0);
                c = __builtin_amdgcn_mfma_f32_16x16x32_f16(w3f[1][mt], a3[u][1], c, 0, 0, 0);
                const float* wv = &w4v[mt].x;
                #pragma unroll
                for (int rr = 0; rr < 4; ++rr)
                    s = fmaf(fmaxf(c[rr], 0.f), wv[rr], s);
            }
            s += __shfl_xor(s, 16);
            s += __shfl_xor(s, 32);
            s += b4v;
            const int  p2  = row0 + u*16 + col;
            const bool vld = (p2 < count);
            const float inv = __builtin_amdgcn_rcpf(rv[u].w + 1e-12f);
            const float wm  = vld ? (s * inv) : 0.f;
            if (cq == 0) {
                acc[0][0] = fmaf(wm, rv[u].x, acc[0][0]);
                acc[0][1] = fmaf(wm, rv[u].y, acc[0][1]);
                acc[0][2] = fmaf(wm, rv[u].z, acc[0][2]);
            } else {
                acc[1][0] = fmaf(wm, rv[u].x, acc[1][0]);
                acc[1][1] = fmaf(wm, rv[u].y, acc[1][1]);
                acc[1][2] = fmaf(wm, rv[u].z, acc[1][2]);
            }
        }
    }

    // ---- butterflies; each pair counted by 4 quads -> x0.25 ----
    #pragma unroll
    for (int cq = 0; cq < 2; ++cq)
        #pragma unroll
        for (int d = 0; d < 3; ++d) {
            float v = acc[cq][d];
            #pragma unroll
            for (int off = 1; off < 64; off <<= 1) v += __shfl_xor(v, off);
            if (lane == 0) wred[wave][cq][d] = v * 0.25f;
        }
    __syncthreads();

    // ---- heads: wave 0 -> q0, wave 1 -> q1 (lane = hidden unit) ----
    if (wave < 2) {
        const int cq = wave;
        float v0 = 0.f, v1 = 0.f, v2 = 0.f;
        #pragma unroll
        for (int w = 0; w < 8; ++w) {
            v0 += wred[w][cq][0]; v1 += wred[w][cq][1]; v2 += wred[w][cq][2];
        }
        float th = fmaf(v0, W5[lane],
                   fmaf(v1, W5[64+lane],
                   fmaf(v2, W5[128+lane], b5[lane])));
        th = fmaxf(th, 0.f);
        float o0 = th * W6[lane*3+0];
        float o1 = th * W6[lane*3+1];
        float o2 = th * W6[lane*3+2];
        #pragma unroll
        for (int off = 1; off < 64; off <<= 1) {
            o0 += __shfl_xor(o0, off);
            o1 += __shfl_xor(o1, off);
            o2 += __shfl_xor(o2, off);
        }
        if (lane == 0) {
            const int qo = blockIdx.x*2 + cq;
            out[qo*3+0] = o0 + b6[0];
            out[qo*3+1] = o1 + b6[1];
            out[qo*3+2] = o2 + b6[2];
        }
    }
}

extern "C" void kernel_launch(void* const* d_in, const int* in_sizes, int n_in,
                              void* d_out, int out_size, void* d_ws, size_t ws_size,
                              hipStream_t stream) {
    const float* atom_pos  = (const float*)d_in[0];
    const float* atom_feat = (const float*)d_in[1];
    const float* query_pos = (const float*)d_in[2];
    const float* W1 = (const float*)d_in[3];  const float* b1 = (const float*)d_in[4];
    const float* W2 = (const float*)d_in[5];  const float* b2 = (const float*)d_in[6];
    const float* W3 = (const float*)d_in[7];  const float* b3 = (const float*)d_in[8];
    const float* W4 = (const float*)d_in[9];  const float* b4 = (const float*)d_in[10];
    const float* W5 = (const float*)d_in[11]; const float* b5 = (const float*)d_in[12];
    const float* W6 = (const float*)d_in[13]; const float* b6 = (const float*)d_in[14];
    float* out = (float*)d_out;
    char*  ws  = (char*)d_ws;   // 16KB frags + 8KB biases

    hipLaunchKernelGGL(repack_kernel, dim3(24), dim3(64), 0, stream,
                       W1, b1, W2, b2, W3, b3, W4, ws);
    hipLaunchKernelGGL(aqfn_kernel, dim3(2048), dim3(512), 0, stream,
                       atom_pos, atom_feat, query_pos, b4, W5, b5, W6, b6,
                       (const char*)ws, out);
}

// Round 14
// 117.259 us; speedup vs baseline: 1.2028x; 1.2028x over previous
//
#include <hip/hip_runtime.h>
#include <math.h>

// AtomQueryFieldNet: NQ=4096, NA=512, pair MLP 18->64->64->32->1, cutoff mask,
// per-query 3-vector reduction, 3->64->3 head.
//
// R14: K=16 MFMA chaining — ZERO inter-layer LDS exchange.
//  - Layout identity: mfma_f32_16x16x16_f16 B-frag k = quad*4+j  ==  C/D row
//    = quad*4+rr. In the transposed form (pairs on N), each layer's f32x4
//    output, relu+cvt'd in-lane, IS the next layer's B-frag (chunk kc = mt).
//    Whole MLP chains in registers: no ds_write/ds_read/lgkmcnt in the chain.
//  - 32 K=16 MFMAs/tile vs 16 K=32: total MFMA issue ~3us aggregate (was 9.4%
//    MfmaUtil of 41us) -> doubling is cheap vs removing 12 DS ops/tile.
//  - LDS ~7KB (rbuf/fbuf only) -> residency VGPR-bound, not LDS-bound.
//  - Structure = R12 (best, 41us): block=query, 4 waves, shared compacted
//    list (2-barrier deterministic prefix), 32-pair chunks round-robin, NT=2.
//  - R13 (8-wave blocks, 50KB LDS) regressed to 64us: reverted.
//  - fp16 in / fp32 accum; absmax ~0.0156.

typedef _Float16 f16x4 __attribute__((ext_vector_type(4)));
typedef _Float16 f16x2 __attribute__((ext_vector_type(2)));
typedef float    f32x4 __attribute__((ext_vector_type(4)));

#define CAP 352   // max in-range atoms/query (geometric max ~270)
#define NT  2     // tiles (16 pairs) interleaved per chunk

// ---- repack: weights -> K=16 MFMA A-fragment order in d_ws ----
// 32 f16x4 frags (8B/lane): f 0..7 L1 (kc*4+mt, kc<2), 8..23 L2 (kc*4+mt,
// kc<4), 24..31 L3 (kc*2+mt, kc<4). elem j: W[k=kc*16+quad*4+j][mt*16+col];
// L1 row 18 = b1 (bias slot). Biases (float4) at +16KB: 0..3 b2, 4..5 b3, 6..7 W4.
__global__ __launch_bounds__(64) void repack_kernel(
    const float* __restrict__ W1, const float* __restrict__ b1,
    const float* __restrict__ W2, const float* __restrict__ b2,
    const float* __restrict__ W3, const float* __restrict__ b3,
    const float* __restrict__ W4, char* __restrict__ ws)
{
    const int b = blockIdx.x, l = threadIdx.x;
    const int col = l & 15, quad = l >> 4;
    if (b < 32) {
        f16x4 v;
        #pragma unroll
        for (int j = 0; j < 4; ++j) {
            float x;
            if (b < 8) {
                const int kc = b >> 2, mt = b & 3;
                const int k = kc*16 + quad*4 + j;
                x = (k < 18) ? W1[k*64 + mt*16 + col]
                             : (k == 18 ? b1[mt*16 + col] : 0.0f);
            } else if (b < 24) {
                const int idx = b - 8, kc = idx >> 2, mt = idx & 3;
                const int k = kc*16 + quad*4 + j;
                x = W2[k*64 + mt*16 + col];
            } else {
                const int idx = b - 24, kc = idx >> 1, mt = idx & 1;
                const int k = kc*16 + quad*4 + j;
                x = W3[k*32 + mt*16 + col];
            }
            v[j] = (_Float16)x;
        }
        *(f16x4*)(ws + (b*64 + l)*8) = v;
    } else {
        const int d = b - 32;
        float o[4];
        #pragma unroll
        for (int rr = 0; rr < 4; ++rr) {
            const int idx = quad*4 + rr;
            if (d < 4)      o[rr] = b2[d*16 + idx];
            else if (d < 6) o[rr] = b3[(d-4)*16 + idx];
            else            o[rr] = W4[(d-6)*16 + idx];
        }
        *(float4*)(ws + 16384 + (d*64 + l)*16) = make_float4(o[0],o[1],o[2],o[3]);
    }
}

__device__ __forceinline__ f16x4 relu_cvt(f32x4 c) {
    return f16x4{(_Float16)fmaxf(c[0],0.f), (_Float16)fmaxf(c[1],0.f),
                 (_Float16)fmaxf(c[2],0.f), (_Float16)fmaxf(c[3],0.f)};
}

__global__ __launch_bounds__(256, 1) void aqfn_kernel(
    const float* __restrict__ atom_pos,   // (512,3)
    const float* __restrict__ atom_feat,  // (512,2)
    const float* __restrict__ query_pos,  // (4096,3)
    const float* __restrict__ b4,         // (1)
    const float* __restrict__ W5, const float* __restrict__ b5,  // (3,64),(64)
    const float* __restrict__ W6, const float* __restrict__ b6,  // (64,3),(3)
    const char*  __restrict__ ws,         // repacked weights
    float* __restrict__ out)              // (4096,3)
{
    __shared__ __align__(16) float4 rbuf[CAP];   // shared compacted list
    __shared__ __align__(16) f16x2  fbuf[CAP];
    __shared__ float wred[4][3];
    __shared__ int   wcnt[4];

    const int tid  = threadIdx.x;
    const int wave = __builtin_amdgcn_readfirstlane(tid >> 6);
    const int lane = tid & 63;
    const int col  = lane & 15;
    const int quad = lane >> 4;
    const int q    = blockIdx.x;

    // ---- fragment preload: 32x 8B + 8x 16B coalesced loads ----
    const f16x4*  wsf = (const f16x4*)ws;
    const float4* wsb = (const float4*)(ws + 16384);
    f16x4 w1f[2][4], w2f[4][4], w3f[4][2];
    #pragma unroll
    for (int kc = 0; kc < 2; ++kc)
        #pragma unroll
        for (int mt = 0; mt < 4; ++mt) w1f[kc][mt] = wsf[(kc*4 + mt)*64 + lane];
    #pragma unroll
    for (int kc = 0; kc < 4; ++kc)
        #pragma unroll
        for (int mt = 0; mt < 4; ++mt) w2f[kc][mt] = wsf[(8 + kc*4 + mt)*64 + lane];
    #pragma unroll
    for (int kc = 0; kc < 4; ++kc)
        #pragma unroll
        for (int mt = 0; mt < 2; ++mt) w3f[kc][mt] = wsf[(24 + kc*2 + mt)*64 + lane];
    float4 b2v[4], b3v[2], w4v[2];
    #pragma unroll
    for (int mt = 0; mt < 4; ++mt) b2v[mt] = wsb[mt*64 + lane];
    #pragma unroll
    for (int mt = 0; mt < 2; ++mt) { b3v[mt] = wsb[(4+mt)*64 + lane];
                                     w4v[mt] = wsb[(6+mt)*64 + lane]; }
    const float b4v = b4[0];

    const float qx = query_pos[q*3+0];
    const float qy = query_pos[q*3+1];
    const float qz = query_pos[q*3+2];

    // ---- pass 1: per-wave ballots over segment [wave*128, +128) ----
    float rxv[2], ryv[2], rzv[2], dv[2], f0v[2], f1v[2];
    unsigned long long msk[2];
    int mycnt = 0;
    #pragma unroll
    for (int it = 0; it < 2; ++it) {
        const int a = wave*128 + it*64 + lane;
        const float rx = qx - atom_pos[a*3+0];
        const float ry = qy - atom_pos[a*3+1];
        const float rz = qz - atom_pos[a*3+2];
        const float ex = __fadd_rn(rx, 1e-12f);
        const float ey = __fadd_rn(ry, 1e-12f);
        const float ez = __fadd_rn(rz, 1e-12f);
        const float dd = __fadd_rn(__fadd_rn(__fmul_rn(ex,ex), __fmul_rn(ey,ey)),
                                   __fmul_rn(ez,ez));
        const float dist = sqrtf(dd);
        rxv[it] = rx; ryv[it] = ry; rzv[it] = rz; dv[it] = dist;
        f0v[it] = atom_feat[a*2+0]; f1v[it] = atom_feat[a*2+1];
        msk[it] = __ballot(dist <= 6.0f);
        mycnt  += (int)__popcll(msk[it]);
    }
    if (lane == 0) wcnt[wave] = mycnt;
    __syncthreads();

    int base = 0, count = 0;
    #pragma unroll
    for (int w = 0; w < 4; ++w) {
        const int c = wcnt[w];
        if (w < wave) base += c;
        count += c;
    }
    if (count > CAP) count = CAP;

    // ---- pass 2: prefix-offset writes into the shared list ----
    {
        int off0 = base;
        #pragma unroll
        for (int it = 0; it < 2; ++it) {
            const bool in = (msk[it] >> lane) & 1ull;
            const int  p  = off0 + (int)__popcll(msk[it] & ((1ull << lane) - 1ull));
            if (in && p < CAP) {
                rbuf[p] = make_float4(rxv[it], ryv[it], rzv[it], dv[it]);
                fbuf[p] = f16x2{(_Float16)f0v[it], (_Float16)f1v[it]};
            }
            off0 += (int)__popcll(msk[it]);
        }
    }
    __syncthreads();

    // ---- MLP over shared list: 32-pair chunks round-robin, all in-register ----
    float wacc0 = 0.f, wacc1 = 0.f, wacc2 = 0.f;
    const int nchunks = (count + (NT*16 - 1)) / (NT*16);

    #pragma unroll 1
    for (int chunk = wave; chunk < nchunks; chunk += 4) {
        const int row0 = chunk * (NT*16);

        float4 rv[NT]; f16x2 ffv[NT];
        #pragma unroll
        for (int u = 0; u < NT; ++u) {
            int pr = row0 + u*16 + col;
            if (pr >= count) pr = count - 1;
            rv[u]  = rbuf[pr];
            ffv[u] = fbuf[pr];
        }

        // X B-frags (K=16 chunks): xa[u][kc][j], k = kc*16 + quad*4 + j
        f16x4 xa[NT][2];
        #pragma unroll
        for (int u = 0; u < NT; ++u) {
            const float dist = rv[u].w;
            #pragma unroll
            for (int kc = 0; kc < 2; ++kc)
                #pragma unroll
                for (int j = 0; j < 4; ++j) {
                    const int k = kc*16 + quad*4 + j;
                    const float tt = dist - 0.4f * (float)(k - 2);  // centers linspace(0,6,16)
                    float v = __expf(-10.0f * tt * tt);
                    v = (k < 18) ? v : 0.0f;
                    _Float16 xv = (_Float16)v;
                    if (k == 18) xv = (_Float16)1.0f;   // bias slot (b1 in W1)
                    if (k == 0)  xv = ffv[u][0];
                    if (k == 1)  xv = ffv[u][1];
                    xa[u][kc][j] = xv;
                }
        }

        // ---- L1: h1^T rows mt*16+quad*4+rr -> directly next-layer B-frag kc=mt ----
        f16x4 a2[NT][4];
        #pragma unroll
        for (int u = 0; u < NT; ++u)
            #pragma unroll
            for (int mt = 0; mt < 4; ++mt) {
                f32x4 c = {0.f, 0.f, 0.f, 0.f};
                c = __builtin_amdgcn_mfma_f32_16x16x16f16(w1f[0][mt], xa[u][0], c, 0, 0, 0);
                c = __builtin_amdgcn_mfma_f32_16x16x16f16(w1f[1][mt], xa[u][1], c, 0, 0, 0);
                a2[u][mt] = relu_cvt(c);
            }

        // ---- L2 ----
        f16x4 a3[NT][4];
        #pragma unroll
        for (int u = 0; u < NT; ++u)
            #pragma unroll
            for (int mt = 0; mt < 4; ++mt) {
                f32x4 c = {b2v[mt].x, b2v[mt].y, b2v[mt].z, b2v[mt].w};
                #pragma unroll
                for (int kc = 0; kc < 4; ++kc)
                    c = __builtin_amdgcn_mfma_f32_16x16x16f16(w2f[kc][mt], a2[u][kc], c, 0, 0, 0);
                a3[u][mt] = relu_cvt(c);
            }

        // ---- L3 + L4 partial + quad-reduce + fused accumulation ----
        #pragma unroll
        for (int u = 0; u < NT; ++u) {
            float s = 0.f;
            #pragma unroll
            for (int mt = 0; mt < 2; ++mt) {
                f32x4 c = {b3v[mt].x, b3v[mt].y, b3v[mt].z, b3v[mt].w};
                #pragma unroll
                for (int kc = 0; kc < 4; ++kc)
                    c = __builtin_amdgcn_mfma_f32_16x16x16f16(w3f[kc][mt], a3[u][kc], c, 0, 0, 0);
                const float* wv = &w4v[mt].x;
                #pragma unroll
                for (int rr = 0; rr < 4; ++rr)
                    s = fmaf(fmaxf(c[rr], 0.f), wv[rr], s);
            }
            s += __shfl_xor(s, 16);
            s += __shfl_xor(s, 32);
            s += b4v;
            const int  p2  = row0 + u*16 + col;
            const bool vld = (p2 < count);
            const float inv = __builtin_amdgcn_rcpf(rv[u].w + 1e-12f);
            const float wm  = vld ? (s * inv) : 0.f;
            wacc0 = fmaf(wm, rv[u].x, wacc0);
            wacc1 = fmaf(wm, rv[u].y, wacc1);
            wacc2 = fmaf(wm, rv[u].z, wacc2);
        }
    }

    // ---- 64-lane butterfly; each pair counted by 4 quads -> x0.25 ----
    #pragma unroll
    for (int off = 1; off < 64; off <<= 1) {
        wacc0 += __shfl_xor(wacc0, off);
        wacc1 += __shfl_xor(wacc1, off);
        wacc2 += __shfl_xor(wacc2, off);
    }
    if (lane == 0) {
        wred[wave][0] = wacc0 * 0.25f;
        wred[wave][1] = wacc1 * 0.25f;
        wred[wave][2] = wacc2 * 0.25f;
    }
    __syncthreads();

    // ---- head: 3 -> 64 -> 3 (wave 0, lane = hidden unit) ----
    if (wave == 0) {
        const float v0 = wred[0][0] + wred[1][0] + wred[2][0] + wred[3][0];
        const float v1 = wred[0][1] + wred[1][1] + wred[2][1] + wred[3][1];
        const float v2 = wred[0][2] + wred[1][2] + wred[2][2] + wred[3][2];
        float th = fmaf(v0, W5[lane],
                   fmaf(v1, W5[64+lane],
                   fmaf(v2, W5[128+lane], b5[lane])));
        th = fmaxf(th, 0.f);
        float o0 = th * W6[lane*3+0];
        float o1 = th * W6[lane*3+1];
        float o2 = th * W6[lane*3+2];
        #pragma unroll
        for (int off = 1; off < 64; off <<= 1) {
            o0 += __shfl_xor(o0, off);
            o1 += __shfl_xor(o1, off);
            o2 += __shfl_xor(o2, off);
        }
        if (lane == 0) {
            out[q*3+0] = o0 + b6[0];
            out[q*3+1] = o1 + b6[1];
            out[q*3+2] = o2 + b6[2];
        }
    }
}

extern "C" void kernel_launch(void* const* d_in, const int* in_sizes, int n_in,
                              void* d_out, int out_size, void* d_ws, size_t ws_size,
                              hipStream_t stream) {
    const float* atom_pos  = (const float*)d_in[0];
    const float* atom_feat = (const float*)d_in[1];
    const float* query_pos = (const float*)d_in[2];
    const float* W1 = (const float*)d_in[3];  const float* b1 = (const float*)d_in[4];
    const float* W2 = (const float*)d_in[5];  const float* b2 = (const float*)d_in[6];
    const float* W3 = (const float*)d_in[7];  const float* b3 = (const float*)d_in[8];
    const float* W4 = (const float*)d_in[9];  const float* b4 = (const float*)d_in[10];
    const float* W5 = (const float*)d_in[11]; const float* b5 = (const float*)d_in[12];
    const float* W6 = (const float*)d_in[13]; const float* b6 = (const float*)d_in[14];
    float* out = (float*)d_out;
    char*  ws  = (char*)d_ws;   // 16KB frags + 8KB biases

    hipLaunchKernelGGL(repack_kernel, dim3(40), dim3(64), 0, stream,
                       W1, b1, W2, b2, W3, b3, W4, ws);
    hipLaunchKernelGGL(aqfn_kernel, dim3(4096), dim3(256), 0, stream,
                       atom_pos, atom_feat, query_pos, b4, W5, b5, W6, b6,
                       (const char*)ws, out);
}